// Round 1
// 136.376 us; speedup vs baseline: 1.0058x; 1.0058x over previous
//
#include <hip/hip_runtime.h>

// FastAttention (Performer linear attention), B=4 H=8 N=4096 D=F=64, fp32.
// Round-4 restructure: 2 kernels, no prep, no atomics, no spill.
//   pass1: grid 32 heads x 64 segs of 64 rows. Issue K/V HBM loads first
//          (8 dwordx4/lane in flight), build bf16 proj*log2e fragment table
//          per-block in LDS (coalesced 16KB proj read, hidden under HBM
//          latency), k' = exp2(k @ proj'), reduce, PLAIN-store per-segment
//          partials (ksum[64]||ctx[64]) to ws[blockIdx*128].
//   pass2: grid 32 heads x 64 segs of 64 rows. Issue Q HBM loads first,
//          build table, redundantly reduce the head's 64 partials
//          (coalesced L2/L3-hot reads) while Q is in flight, then
//          out = q'*ctx/(q'.(ksum+1e-6)).
// Column permutation: MFMA tile ft computes feature f = fp*4+ft (fp=lane&15),
// so V loads, stats and out stores are all dwordx4.
// Register budget: per-block live set ~90 VGPRs << 128 cap of (256,4) —
// the round-3 champion's 128-row pass1 needed ~135+ at the same cap (spill).

#define NHEADS 32
#define SEQ    4096
#define DDIM   64
#define LOG2E 1.44269504088896341f

typedef __attribute__((ext_vector_type(8))) short short8;
typedef __attribute__((ext_vector_type(4))) float floatx4;

__device__ __forceinline__ short f2bf(float x) {
    unsigned int u = __float_as_uint(x);
    u += 0x7fffu + ((u >> 16) & 1u);
    return (short)(u >> 16);
}

__device__ __forceinline__ short8 cvt8(floatx4 a, floatx4 b) {
    short8 t;
    t[0] = f2bf(a[0]); t[1] = f2bf(a[1]); t[2] = f2bf(a[2]); t[3] = f2bf(a[3]);
    t[4] = f2bf(b[0]); t[5] = f2bf(b[1]); t[6] = f2bf(b[2]); t[7] = f2bf(b[3]);
    return t;
}

// Build the bf16(proj*log2e) fragment table in LDS.
// Table read layout (per lane = g*16+fp): tbl[(ft*2+half)*512 + lane*8 + j]
//   = bf16(proj[(fp*4+ft)*64 + half*32 + g*8 + j] * LOG2E)
// Each thread loads 16 contiguous proj floats (fully coalesced) and scatters.
__device__ __forceinline__ void build_tbl(const float* __restrict__ proj,
                                          int tid, short* tbl) {
    const float* pp = proj + tid * 16;
    floatx4 p0 = *(const floatx4*)(pp);
    floatx4 p1 = *(const floatx4*)(pp + 4);
    floatx4 p2 = *(const floatx4*)(pp + 8);
    floatx4 p3 = *(const floatx4*)(pp + 12);
    float vals[16];
    *(floatx4*)(vals)      = p0;
    *(floatx4*)(vals + 4)  = p1;
    *(floatx4*)(vals + 8)  = p2;
    *(floatx4*)(vals + 12) = p3;
    const int f     = tid >> 2;         // feature row of proj
    const int dbase = (tid & 3) * 16;   // starting d within the row
    const int ft    = f & 3;
    const int fpp   = f >> 2;
#pragma unroll
    for (int i = 0; i < 16; ++i) {
        int d    = dbase + i;
        int half = d >> 5;
        int gg   = (d >> 3) & 3;
        int j    = d & 7;
        tbl[(ft * 2 + half) * 512 + (gg * 16 + fpp) * 8 + j] = f2bf(vals[i] * LOG2E);
    }
}

__global__ __launch_bounds__(256, 4) void fa_pass1(const float* __restrict__ K,
                                                   const float* __restrict__ V,
                                                   const float* __restrict__ proj,
                                                   float* __restrict__ ws) {
    const int head = blockIdx.x >> 6;   // 32 heads x 64 segments of 64 rows
    const int seg  = blockIdx.x & 63;
    const int tid  = threadIdx.x;
    const int w    = tid >> 6;
    const int lane = tid & 63;
    const int fp   = lane & 15;
    const int g    = lane >> 4;
    const long hbase = (long)head * SEQ;
    const int rowb = seg * 64 + w * 16;

    __shared__ __align__(16) short tbl[4096];
    __shared__ __align__(16) float red[4][128];

    // ---- issue all HBM loads first (8 dwordx4/lane in flight)
    const float* ap = K + (hbase + rowb + fp) * DDIM;
    floatx4 kraw[4];
    kraw[0] = *(const floatx4*)(ap + g * 8);
    kraw[1] = *(const floatx4*)(ap + g * 8 + 4);
    kraw[2] = *(const floatx4*)(ap + 32 + g * 8);
    kraw[3] = *(const floatx4*)(ap + 32 + g * 8 + 4);
    floatx4 vraw[4];
#pragma unroll
    for (int r = 0; r < 4; ++r)
        vraw[r] = *(const floatx4*)(V + (hbase + rowb + g * 4 + r) * DDIM + fp * 4);

    // ---- table build (L2-hot proj) overlaps the in-flight HBM loads
    build_tbl(proj, tid, tbl);
    __syncthreads();

    short8 bfrag[4][2];
#pragma unroll
    for (int ft = 0; ft < 4; ++ft)
#pragma unroll
        for (int h = 0; h < 2; ++h)
            bfrag[ft][h] = *(const short8*)(tbl + (ft * 2 + h) * 512 + lane * 8);

    short8 a0 = cvt8(kraw[0], kraw[1]);
    short8 a1 = cvt8(kraw[2], kraw[3]);

    floatx4 acc[4];
#pragma unroll
    for (int ft = 0; ft < 4; ++ft) {
        floatx4 z = {0.f, 0.f, 0.f, 0.f};
        z = __builtin_amdgcn_mfma_f32_16x16x32_bf16(a0, bfrag[ft][0], z, 0, 0, 0);
        z = __builtin_amdgcn_mfma_f32_16x16x32_bf16(a1, bfrag[ft][1], z, 0, 0, 0);
        acc[ft] = z;
    }

    // C layout: col f = fp*4+ft, row = rowb + g*4 + r
    float ksum[4] = {0.f, 0.f, 0.f, 0.f};
    float ctx[4]  = {0.f, 0.f, 0.f, 0.f};
#pragma unroll
    for (int r = 0; r < 4; ++r)
#pragma unroll
        for (int ft = 0; ft < 4; ++ft) {
            float kp = __builtin_amdgcn_exp2f(acc[ft][r]);
            ksum[ft] += kp;
            ctx[ft]  += kp * vraw[r][ft];
        }

#pragma unroll
    for (int ft = 0; ft < 4; ++ft) {
        ksum[ft] += __shfl_xor(ksum[ft], 16); ksum[ft] += __shfl_xor(ksum[ft], 32);
        ctx[ft]  += __shfl_xor(ctx[ft], 16);  ctx[ft]  += __shfl_xor(ctx[ft], 32);
    }

    if (lane < 16) {
#pragma unroll
        for (int ft = 0; ft < 4; ++ft) {
            red[w][fp * 4 + ft]      = ksum[ft];
            red[w][64 + fp * 4 + ft] = ctx[ft];
        }
    }
    __syncthreads();
    if (tid < 128) {
        float s = red[0][tid] + red[1][tid] + red[2][tid] + red[3][tid];
        ws[(long)blockIdx.x * 128 + tid] = s;   // plain store — no atomics
    }
}

__global__ __launch_bounds__(256, 4) void fa_pass2(const float* __restrict__ Q,
                                                   const float* __restrict__ proj,
                                                   const float* __restrict__ ws,
                                                   float* __restrict__ out) {
    const int head = blockIdx.x >> 6;   // 32 heads x 64 segments of 64 rows
    const int seg  = blockIdx.x & 63;
    const int tid  = threadIdx.x;
    const int w    = tid >> 6;
    const int lane = tid & 63;
    const int fp   = lane & 15;
    const int g    = lane >> 4;
    const long hbase = (long)head * SEQ;
    const int rowb = seg * 64 + w * 16;

    __shared__ __align__(16) short tbl[4096];
    __shared__ __align__(16) float sred[2][128];

    // ---- issue the HBM Q loads FIRST
    const float* ap = Q + (hbase + rowb + fp) * DDIM;
    floatx4 qraw[4];
    qraw[0] = *(const floatx4*)(ap + g * 8);
    qraw[1] = *(const floatx4*)(ap + g * 8 + 4);
    qraw[2] = *(const floatx4*)(ap + 32 + g * 8);
    qraw[3] = *(const floatx4*)(ap + 32 + g * 8 + 4);

    // ---- per-head stat reduction: 64 partials x 128 floats, coalesced,
    //      L2/L3-hot. Thread t sums partials [ph*32, ph*32+32) of element e.
    const int e  = tid & 127;
    const int ph = tid >> 7;
    const float* wp = ws + (long)head * 8192 + (long)ph * 4096 + e;
    float s = 0.f;
#pragma unroll
    for (int p = 0; p < 32; ++p) s += wp[p * 128];

    build_tbl(proj, tid, tbl);
    sred[ph][e] = s;
    __syncthreads();

    short8 bfrag[4][2];
#pragma unroll
    for (int ft = 0; ft < 4; ++ft)
#pragma unroll
        for (int h = 0; h < 2; ++h)
            bfrag[ft][h] = *(const short8*)(tbl + (ft * 2 + h) * 512 + lane * 8);

    floatx4 k0 = *(const floatx4*)(&sred[0][fp * 4]);
    floatx4 k1 = *(const floatx4*)(&sred[1][fp * 4]);
    floatx4 c0 = *(const floatx4*)(&sred[0][64 + fp * 4]);
    floatx4 c1 = *(const floatx4*)(&sred[1][64 + fp * 4]);
    floatx4 ksr, ctxr;
#pragma unroll
    for (int ft = 0; ft < 4; ++ft) {
        ksr[ft]  = k0[ft] + k1[ft] + 1e-6f;
        ctxr[ft] = c0[ft] + c1[ft];
    }

    short8 afrag0 = cvt8(qraw[0], qraw[1]);
    short8 afrag1 = cvt8(qraw[2], qraw[3]);

    float qp[4][4];
    float denom[4] = {0.f, 0.f, 0.f, 0.f};
#pragma unroll
    for (int ft = 0; ft < 4; ++ft) {
        floatx4 z = {0.f, 0.f, 0.f, 0.f};
        z = __builtin_amdgcn_mfma_f32_16x16x32_bf16(afrag0, bfrag[ft][0], z, 0, 0, 0);
        z = __builtin_amdgcn_mfma_f32_16x16x32_bf16(afrag1, bfrag[ft][1], z, 0, 0, 0);
#pragma unroll
        for (int r = 0; r < 4; ++r) {
            float qe = __builtin_amdgcn_exp2f(z[r]);
            qp[ft][r] = qe;
            denom[r] += qe * ksr[ft];
        }
    }

#pragma unroll
    for (int r = 0; r < 4; ++r) {
        denom[r] += __shfl_xor(denom[r], 1);
        denom[r] += __shfl_xor(denom[r], 2);
        denom[r] += __shfl_xor(denom[r], 4);
        denom[r] += __shfl_xor(denom[r], 8);
        denom[r] = 1.0f / denom[r];
    }

#pragma unroll
    for (int r = 0; r < 4; ++r) {
        floatx4 o;
#pragma unroll
        for (int ft = 0; ft < 4; ++ft)
            o[ft] = qp[ft][r] * ctxr[ft] * denom[r];
        *(floatx4*)(out + (hbase + rowb + g * 4 + r) * DDIM + fp * 4) = o;
    }
}

extern "C" void kernel_launch(void* const* d_in, const int* in_sizes, int n_in,
                              void* d_out, int out_size, void* d_ws, size_t ws_size,
                              hipStream_t stream) {
    const float* q    = (const float*)d_in[0];
    const float* k    = (const float*)d_in[1];
    const float* v    = (const float*)d_in[2];
    const float* proj = (const float*)d_in[3];
    float* out = (float*)d_out;
    float* ws  = (float*)d_ws;

    fa_pass1<<<NHEADS * 64, 256, 0, stream>>>(k, v, proj, ws);
    fa_pass2<<<NHEADS * 64, 256, 0, stream>>>(q, proj, ws, out);
}